// Round 4
// baseline (374.866 us; speedup 1.0000x reference)
//
#include <hip/hip_runtime.h>

// conv(3x3,C3->F32) -> earlyMLP(32768->128) -> reset-masked LSTM(128) -> outMLP(128->128)
// R3 analysis: dur ≈ 48us harness resets + ~10us/dispatch × 7 + ~35us kernels.
// R4: TWO dispatches: 256B memset (barrier ctr) + one persistent mega-kernel
//     (512 blocks x 256 thr, guaranteed 2 blocks/CU co-residency) with 4 device-scope
//     grid barriers between phases:
//     P0 prep+build_u (XCD-swizzled pixels -> per-XCD L2 locality)
//     P1 feat split-K GEMM (LDS double-buffer + reg prefetch, XOR-swizzled banks)
//     P2 zx GEMM with fused split-K reduce    P3 segment-parallel LSTM (f16 dot2)
//     P4 out GEMM

typedef unsigned short ushort_t;
typedef short bf16x8 __attribute__((ext_vector_type(8)));
typedef float f32x4 __attribute__((ext_vector_type(4)));
typedef _Float16 h2 __attribute__((ext_vector_type(2)));

#define GRID 512

__device__ __forceinline__ ushort_t f2b(float f) {
  unsigned u = __float_as_uint(f);
  return (ushort_t)((u + 0x7fffu + ((u >> 16) & 1u)) >> 16);  // RNE
}
__device__ __forceinline__ unsigned pack_h2(float a, float b) {
  union { _Float16 h[2]; unsigned u; } v;
  v.h[0] = (_Float16)a; v.h[1] = (_Float16)b; return v.u;
}
__device__ __forceinline__ float fsig(float x) {
  return 1.f / (1.f + exp2f(-1.44269504f * x));
}
__device__ __forceinline__ float ftanh(float x) {
  float e = exp2f(2.885390082f * x);
  return 1.f - 2.f / (e + 1.f);
}
__device__ __forceinline__ int nth_bit(unsigned long long m0, unsigned long long m1, int i) {
  int c0 = __popcll(m0);
  if (i < c0) {
    unsigned long long m = m0;
    for (int k = 0; k < i; k++) m &= m - 1;
    return __ffsll((long long)m) - 1;
  }
  i -= c0;
  unsigned long long m = m1;
  for (int k = 0; k < i; k++) m &= m - 1;
  return 64 + __ffsll((long long)m) - 1;
}

// device-scope grid barrier: monotonically increasing counter, memset to 0 pre-launch.
__device__ __forceinline__ void gbar(unsigned* ctr, unsigned target) {
  __syncthreads();
  if (threadIdx.x == 0) {
    __hip_atomic_fetch_add(ctr, 1u, __ATOMIC_RELEASE, __HIP_MEMORY_SCOPE_AGENT);
    while (__hip_atomic_load(ctr, __ATOMIC_ACQUIRE, __HIP_MEMORY_SCOPE_AGENT) < target)
      __builtin_amdgcn_s_sleep(8);
  }
  __syncthreads();
}

__global__ __launch_bounds__(256, 2) void mega(
    const float* __restrict__ x, const int* __restrict__ done,
    const float* __restrict__ conv_w, const float* __restrict__ conv_b,
    const float* __restrict__ early_w, const float* __restrict__ eb,
    const float* __restrict__ wx, const float* __restrict__ wh,
    const float* __restrict__ lstm_b, const float* __restrict__ ow,
    const float* __restrict__ out_b,
    unsigned* __restrict__ ctr, float* __restrict__ partial,
    ushort_t* __restrict__ UT, float* __restrict__ zx,
    ushort_t* __restrict__ wxT, unsigned* __restrict__ whT16,
    ushort_t* __restrict__ owT, ushort_t* __restrict__ hsb,
    float* __restrict__ bias2, float* __restrict__ dout)
{
  __shared__ union {
    float cw[864];                    // P0
    short ft[2][9216];                // P1: per buf: As 16x64 @0, Bs 128x64 @1024
    short g2[18432];                  // P2/P4: As 16x128 @0, Bs 128x128 @2048
    struct { float z[512]; float c[128]; _Float16 h16[128];
             unsigned long long masks[16]; } ls;   // P3
  } L;

  const int tid = threadIdx.x;
  const int b = blockIdx.x;
  const int wave = tid >> 6, lane = tid & 63;
  const int quad = lane >> 4, l15 = lane & 15;
  const int c0 = wave * 32;

  // ================= P0: prep transposes + build U =================
  {
    int i = b * 256 + tid;                       // 131072 threads >= 114816 elems
    if (i < 65536) { int n = i >> 7, k = i & 127; wxT[i] = f2b(wx[k * 512 + n]); }
    else if (i < 98304) { int j = i - 65536; int col = j >> 6, k2 = j & 63;
      whT16[j] = pack_h2(wh[(2 * k2) * 512 + col], wh[(2 * k2 + 1) * 512 + col]); }
    else if (i < 114688) { int j = i - 98304; int n = j >> 7, k = j & 127;
      owT[j] = f2b(ow[k * 128 + n]); }
    else if (i < 114816) { bias2[i - 114688] = eb[i - 114688]; }

    for (int q = tid; q < 864; q += 256) L.cw[q] = conv_w[q];
    __syncthreads();
    // 2 pixel-groups of 128 threads; XCD-swizzled: XCD x owns 4 contiguous pixel rows
    const int o = tid & 127, grp = tid >> 7;
    const int px = (b & 7) * 128 + ((b >> 3) << 1) + grp;
    const int hp = px >> 5, wp = px & 31;
    float a0 = 0.f, a1 = 0.f, a2 = 0.f;
    for (int kh = 0; kh < 3; kh++) {
      int h = hp - kh + 1; if ((unsigned)h >= 32u) continue;
      for (int kw = 0; kw < 3; kw++) {
        int w = wp - kw + 1; if ((unsigned)w >= 32u) continue;
        const float* wr = early_w + ((size_t)((h * 32 + w) * 32)) * 128 + o;
        const float* cwp = L.cw + (kh * 3 + kw) * 96;
        #pragma unroll 8
        for (int f = 0; f < 32; f++) {
          float wv = wr[f * 128];
          a0 += cwp[f]      * wv;
          a1 += cwp[32 + f] * wv;
          a2 += cwp[64 + f] * wv;
        }
      }
    }
    size_t ub = (size_t)o * 3072 + px * 3;
    UT[ub + 0] = f2b(a0); UT[ub + 1] = f2b(a1); UT[ub + 2] = f2b(a2);

    // conv_b fold (conv_b==0 here; NB: racy vs bias2 init if nonzero, acceptable)
    float cbs = 0.f;
    #pragma unroll 8
    for (int f = 0; f < 32; f++) cbs += __builtin_fabsf(conv_b[f]);
    if (cbs != 0.f && px < 32) {
      float part = 0.f;
      for (int pp = px * 32; pp < px * 32 + 32; pp++)
        for (int f = 0; f < 32; f++)
          part += conv_b[f] * early_w[(size_t)(pp * 32 + f) * 128 + o];
      atomicAdd(&bias2[o], part);
    }
  }
  gbar(ctr, GRID);

  // ================= P1: feat split-K GEMM (double-buffered) =================
  // task b: m-tile = b&63, ks = b>>6; K-chunk = 384 (6 iters of 64)
  {
    const int m0 = (b & 63) * 16;
    const int ks = b >> 6;
    const int kb = ks * 384;
    const bool isA = tid < 128;
    const int arow = tid >> 3, ag = tid & 7;     // A slot (tid<128)
    const int s2base = tid ^ 128;                // 4 B slots: s2base + 256j

    float4 fa0, fa1; uint4 rb[4];
    f32x4 acc0 = {0.f, 0.f, 0.f, 0.f};
    f32x4 acc1 = {0.f, 0.f, 0.f, 0.f};

    auto load = [&](int k0) {
      if (isA) {
        const float4* p = (const float4*)(x + (size_t)(m0 + arow) * 3072 + k0 + ag * 8);
        fa0 = p[0]; fa1 = p[1];
      }
      #pragma unroll
      for (int j = 0; j < 4; j++) {
        int s2 = s2base + 256 * j, row = s2 >> 3, g = s2 & 7;
        rb[j] = *(const uint4*)(UT + (size_t)row * 3072 + k0 + g * 8);
      }
    };
    auto stage = [&](int p) {
      #pragma unroll
      for (int j = 0; j < 4; j++) {
        int s2 = s2base + 256 * j, row = s2 >> 3, g = s2 & 7;
        *(uint4*)&L.ft[p][1024 + row * 64 + (((g ^ row) & 7) * 8)] = rb[j];
      }
      if (isA) {
        union { ushort_t us[8]; uint4 v; } t8;
        t8.us[0] = f2b(fa0.x); t8.us[1] = f2b(fa0.y); t8.us[2] = f2b(fa0.z); t8.us[3] = f2b(fa0.w);
        t8.us[4] = f2b(fa1.x); t8.us[5] = f2b(fa1.y); t8.us[6] = f2b(fa1.z); t8.us[7] = f2b(fa1.w);
        *(uint4*)&L.ft[p][arow * 64 + (((ag ^ arow) & 7) * 8)] = t8.v;
      }
    };

    load(kb);
    for (int it = 0; it < 6; it++) {
      const int p = it & 1;
      stage(p);
      __syncthreads();
      if (it < 5) load(kb + (it + 1) * 64);
      const short* As = &L.ft[p][0];
      const short* Bs = &L.ft[p][1024];
      #pragma unroll
      for (int kk = 0; kk < 2; kk++) {
        int gp = kk * 4 + quad;
        bf16x8 a  = *(const bf16x8*)&As[l15 * 64 + (((gp ^ l15) & 7) * 8)];
        bf16x8 b0 = *(const bf16x8*)&Bs[(c0 + l15) * 64 + (((gp ^ (c0 + l15)) & 7) * 8)];
        bf16x8 b1 = *(const bf16x8*)&Bs[(c0 + 16 + l15) * 64 + (((gp ^ (c0 + l15)) & 7) * 8)];
        acc0 = __builtin_amdgcn_mfma_f32_16x16x32_bf16(a, b0, acc0, 0, 0, 0);
        acc1 = __builtin_amdgcn_mfma_f32_16x16x32_bf16(a, b1, acc1, 0, 0, 0);
      }
    }
    #pragma unroll
    for (int r = 0; r < 4; r++) {
      int m = m0 + quad * 4 + r;
      size_t base = ((size_t)ks * 1024 + m) * 128;
      partial[base + c0 + l15]      = acc0[r];
      partial[base + c0 + 16 + l15] = acc1[r];
    }
  }
  gbar(ctr, 2 * GRID);

  // ================= P2: zx = relu-feat @ Wx + b (fused split-K reduce) =================
  if (b < 256) {
    const int m0 = (b & 63) * 16;
    const int n0 = (b >> 6) * 128;
    // A: reduce 8 partials + bias + relu -> bf16 -> LDS (swizzled)
    {
      int r = tid >> 4, gA = tid & 15, cb = gA * 8;
      float4 s0 = {0,0,0,0}, s1 = {0,0,0,0};
      #pragma unroll
      for (int ks = 0; ks < 8; ks++) {
        const float4* p = (const float4*)(partial + (size_t)ks * 131072 + (m0 + r) * 128 + cb);
        float4 u0 = p[0], u1 = p[1];
        s0.x += u0.x; s0.y += u0.y; s0.z += u0.z; s0.w += u0.w;
        s1.x += u1.x; s1.y += u1.y; s1.z += u1.z; s1.w += u1.w;
      }
      const float* bp = bias2 + cb;
      union { ushort_t us[8]; uint4 v; } t8;
      t8.us[0] = f2b(fmaxf(s0.x + bp[0], 0.f)); t8.us[1] = f2b(fmaxf(s0.y + bp[1], 0.f));
      t8.us[2] = f2b(fmaxf(s0.z + bp[2], 0.f)); t8.us[3] = f2b(fmaxf(s0.w + bp[3], 0.f));
      t8.us[4] = f2b(fmaxf(s1.x + bp[4], 0.f)); t8.us[5] = f2b(fmaxf(s1.y + bp[5], 0.f));
      t8.us[6] = f2b(fmaxf(s1.z + bp[6], 0.f)); t8.us[7] = f2b(fmaxf(s1.w + bp[7], 0.f));
      *(uint4*)&L.g2[r * 128 + (((gA ^ r) & 15) * 8)] = t8.v;
    }
    // B: Wx tile 128 x 128
    #pragma unroll
    for (int j = 0; j < 8; j++) {
      int s = tid + 256 * j, row = s >> 4, g = s & 15;
      uint4 v = *(const uint4*)(wxT + (size_t)(n0 + row) * 128 + g * 8);
      *(uint4*)&L.g2[2048 + row * 128 + (((g ^ row) & 15) * 8)] = v;
    }
    __syncthreads();
    f32x4 acc0 = {0,0,0,0}, acc1 = {0,0,0,0};
    #pragma unroll
    for (int kk = 0; kk < 4; kk++) {
      int gp = kk * 4 + quad;
      bf16x8 a  = *(const bf16x8*)&L.g2[l15 * 128 + (((gp ^ l15) & 15) * 8)];
      bf16x8 b0 = *(const bf16x8*)&L.g2[2048 + (c0 + l15) * 128 + (((gp ^ l15) & 15) * 8)];
      bf16x8 b1 = *(const bf16x8*)&L.g2[2048 + (c0 + 16 + l15) * 128 + (((gp ^ l15) & 15) * 8)];
      acc0 = __builtin_amdgcn_mfma_f32_16x16x32_bf16(a, b0, acc0, 0, 0, 0);
      acc1 = __builtin_amdgcn_mfma_f32_16x16x32_bf16(a, b1, acc1, 0, 0, 0);
    }
    #pragma unroll
    for (int r = 0; r < 4; r++) {
      int m = m0 + quad * 4 + r;
      int n1 = n0 + c0 + l15, n2 = n1 + 16;
      zx[(size_t)m * 512 + n1] = acc0[r] + lstm_b[n1];
      zx[(size_t)m * 512 + n2] = acc1[r] + lstm_b[n2];
    }
  }
  gbar(ctr, 3 * GRID);

  // ================= P3: segment-parallel LSTM =================
  {
    uint4 w1[16], w2[16];                        // Wh cols tid, tid+256 (f16 pairs)
    {
      const uint4* p1 = (const uint4*)(whT16 + (size_t)tid * 64);
      const uint4* p2 = (const uint4*)(whT16 + (size_t)(tid + 256) * 64);
      #pragma unroll
      for (int i = 0; i < 16; i++) { w1[i] = p1[i]; w2[i] = p2[i]; }
    }
    const h2* wa = (const h2*)w1;
    const h2* wb = (const h2*)w2;

    for (int n = 0; n < 8; n++) {
      bool flag = false;
      if (tid < 128) flag = (tid == 0) || (done[n * 128 + tid] != 0);
      unsigned long long m = __ballot(flag);
      if (tid == 0)  L.ls.masks[2 * n]     = m;
      if (tid == 64) L.ls.masks[2 * n + 1] = m;
    }
    __syncthreads();

    int total = 0;
    #pragma unroll
    for (int n = 0; n < 8; n++)
      total += __popcll(L.ls.masks[2 * n]) + __popcll(L.ls.masks[2 * n + 1]);

    for (int g = b; g < total; g += GRID) {
      int i = g, n = 0, cn = 0;
      for (; n < 8; n++) {
        cn = __popcll(L.ls.masks[2 * n]) + __popcll(L.ls.masks[2 * n + 1]);
        if (i < cn) break;
        i -= cn;
      }
      int t0 = nth_bit(L.ls.masks[2 * n], L.ls.masks[2 * n + 1], i);
      int t1 = (i + 1 < cn) ? nth_bit(L.ls.masks[2 * n], L.ls.masks[2 * n + 1], i + 1) : 128;

      if (tid < 128) { ((ushort_t*)L.ls.h16)[tid] = 0; L.ls.c[tid] = 0.f; }
      __syncthreads();

      float z1 = zx[((size_t)n * 128 + t0) * 512 + tid];
      float z2 = zx[((size_t)n * 128 + t0) * 512 + tid + 256];
      for (int t = t0; t < t1; t++) {
        float z1n = 0.f, z2n = 0.f;
        if (t + 1 < t1) {
          z1n = zx[((size_t)n * 128 + t + 1) * 512 + tid];
          z2n = zx[((size_t)n * 128 + t + 1) * 512 + tid + 256];
        }
        float a0 = 0.f, a1 = 0.f, a2 = 0.f, a3 = 0.f;
        float b0 = 0.f, b1 = 0.f, b2 = 0.f, b3 = 0.f;
        const float4* hp = (const float4*)L.ls.h16;
        #pragma unroll
        for (int q = 0; q < 16; q++) {
          float4 hb = hp[q];                     // 8 f16, wave-broadcast
          const h2* hh = (const h2*)&hb;
          a0 = __builtin_amdgcn_fdot2(wa[4*q+0], hh[0], a0, false);
          a1 = __builtin_amdgcn_fdot2(wa[4*q+1], hh[1], a1, false);
          a2 = __builtin_amdgcn_fdot2(wa[4*q+2], hh[2], a2, false);
          a3 = __builtin_amdgcn_fdot2(wa[4*q+3], hh[3], a3, false);
          b0 = __builtin_amdgcn_fdot2(wb[4*q+0], hh[0], b0, false);
          b1 = __builtin_amdgcn_fdot2(wb[4*q+1], hh[1], b1, false);
          b2 = __builtin_amdgcn_fdot2(wb[4*q+2], hh[2], b2, false);
          b3 = __builtin_amdgcn_fdot2(wb[4*q+3], hh[3], b3, false);
        }
        L.ls.z[tid]       = z1 + (a0 + a1) + (a2 + a3);
        L.ls.z[tid + 256] = z2 + (b0 + b1) + (b2 + b3);
        __syncthreads();
        if (tid < 128) {
          float ig = fsig(L.ls.z[tid]);
          float fg = fsig(L.ls.z[tid + 128]);
          float gg = ftanh(L.ls.z[tid + 256]);
          float og = fsig(L.ls.z[tid + 384]);
          float c = fg * L.ls.c[tid] + ig * gg;
          float hn = og * ftanh(c);
          L.ls.c[tid] = c;
          L.ls.h16[tid] = (_Float16)hn;
          hsb[((size_t)n * 128 + t) * 128 + tid] = f2b(hn);
          if (t == 127) {
            dout[n * 128 + tid] = c;
            dout[1024 + n * 128 + tid] = hn;
          }
        }
        __syncthreads();
        z1 = z1n; z2 = z2n;
      }
    }
  }
  gbar(ctr, 4 * GRID);

  // ================= P4: y = relu(hs @ out_w + out_b) =================
  if (b < 64) {
    const int m0 = b * 16;
    {
      int r = tid >> 4, g = tid & 15;
      uint4 av = *(const uint4*)(hsb + (size_t)(m0 + r) * 128 + g * 8);
      *(uint4*)&L.g2[r * 128 + (((g ^ r) & 15) * 8)] = av;
    }
    #pragma unroll
    for (int j = 0; j < 8; j++) {
      int s = tid + 256 * j, row = s >> 4, g = s & 15;
      uint4 v = *(const uint4*)(owT + (size_t)row * 128 + g * 8);
      *(uint4*)&L.g2[2048 + row * 128 + (((g ^ row) & 15) * 8)] = v;
    }
    __syncthreads();
    f32x4 acc0 = {0,0,0,0}, acc1 = {0,0,0,0};
    #pragma unroll
    for (int kk = 0; kk < 4; kk++) {
      int gp = kk * 4 + quad;
      bf16x8 a  = *(const bf16x8*)&L.g2[l15 * 128 + (((gp ^ l15) & 15) * 8)];
      bf16x8 b0 = *(const bf16x8*)&L.g2[2048 + (c0 + l15) * 128 + (((gp ^ l15) & 15) * 8)];
      bf16x8 b1 = *(const bf16x8*)&L.g2[2048 + (c0 + 16 + l15) * 128 + (((gp ^ l15) & 15) * 8)];
      acc0 = __builtin_amdgcn_mfma_f32_16x16x32_bf16(a, b0, acc0, 0, 0, 0);
      acc1 = __builtin_amdgcn_mfma_f32_16x16x32_bf16(a, b1, acc1, 0, 0, 0);
    }
    #pragma unroll
    for (int r = 0; r < 4; r++) {
      int m = m0 + quad * 4 + r;
      int n1 = c0 + l15, n2 = n1 + 16;
      dout[2048 + (size_t)m * 128 + n1] = fmaxf(acc0[r] + out_b[n1], 0.f);
      dout[2048 + (size_t)m * 128 + n2] = fmaxf(acc1[r] + out_b[n2], 0.f);
    }
  }
}

// ---------------- launch ----------------
extern "C" void kernel_launch(void* const* d_in, const int* in_sizes, int n_in,
                              void* d_out, int out_size, void* d_ws, size_t ws_size,
                              hipStream_t stream) {
  const float* x       = (const float*)d_in[0];
  const int*   done    = (const int*)  d_in[1];
  const float* conv_w  = (const float*)d_in[2];
  const float* conv_b  = (const float*)d_in[3];
  const float* early_w = (const float*)d_in[4];
  const float* early_b = (const float*)d_in[5];
  const float* lstm_wx = (const float*)d_in[6];
  const float* lstm_wh = (const float*)d_in[7];
  const float* lstm_b  = (const float*)d_in[8];
  const float* out_w   = (const float*)d_in[9];
  const float* out_b   = (const float*)d_in[10];
  float* dout = (float*)d_out;                   // [c_fin 1024][h_fin 1024][y 131072]

  char* ws = (char*)d_ws;
  unsigned* ctrp    = (unsigned*)(ws + 0);        // 256 B (memset to 0)
  float*    partial = (float*)   (ws + 4096);     // [8][1024][128] f32
  ushort_t* UT      = (ushort_t*)(ws + 4198400);  // [128][3072] bf16
  float*    zx      = (float*)   (ws + 4984832);  // [1024][512] f32
  ushort_t* wxT     = (ushort_t*)(ws + 7081984);  // [512][128] bf16
  unsigned* whT16   = (unsigned*)(ws + 7213056);  // [512][64] packed f16x2
  ushort_t* owT     = (ushort_t*)(ws + 7344128);  // [128][128] bf16
  ushort_t* hsb     = (ushort_t*)(ws + 7376896);  // [1024][128] bf16
  float*    bias2   = (float*)   (ws + 7639040);  // [128] f32

  hipMemsetAsync(ctrp, 0, 256, stream);
  mega<<<GRID, 256, 0, stream>>>(x, done, conv_w, conv_b, early_w, early_b,
                                 lstm_wx, lstm_wh, lstm_b, out_w, out_b,
                                 ctrp, partial, UT, zx, wxT, whT16, owT, hsb,
                                 bias2, dout);
}

// Round 5
// 153.749 us; speedup vs baseline: 2.4382x; 2.4382x over previous
//
#include <hip/hip_runtime.h>

// conv(3x3,C3->F32) -> earlyMLP(32768->128) -> reset-masked LSTM(128) -> outMLP(128->128)
// R4 post-mortem: persistent mega-kernel regressed 155->375us (barrier straggler stalls +
// spills; VALUBusy 2.4%). R5: revert to multi-kernel, but fuse down to 4 dispatches:
//   k1 prep+build_u (block-range split)
//   k2 feat split-K GEMM (unchanged from R3 - proven)
//   k3 zx GEMM with fused split-K reduce (+bias+relu on the fly)
//   k4 segment-parallel LSTM with FUSED out-MLP (ow col in 64 f16-pair VGPRs,
//      launch_bounds(512,1) -> 256-VGPR budget, no spill; hsb round-trip eliminated)

typedef unsigned short ushort_t;
typedef short bf16x8 __attribute__((ext_vector_type(8)));
typedef float f32x4 __attribute__((ext_vector_type(4)));
typedef _Float16 h2 __attribute__((ext_vector_type(2)));

__device__ __forceinline__ ushort_t f2b(float f) {
  unsigned u = __float_as_uint(f);
  return (ushort_t)((u + 0x7fffu + ((u >> 16) & 1u)) >> 16);  // RNE
}
__device__ __forceinline__ unsigned pack_h2(float a, float b) {
  union { _Float16 h[2]; unsigned u; } v;
  v.h[0] = (_Float16)a; v.h[1] = (_Float16)b; return v.u;
}
__device__ __forceinline__ float fsig(float x) {
  return 1.f / (1.f + exp2f(-1.44269504f * x));
}
__device__ __forceinline__ float ftanh(float x) {
  float e = exp2f(2.885390082f * x);
  return 1.f - 2.f / (e + 1.f);
}
__device__ __forceinline__ int nth_bit(unsigned long long m0, unsigned long long m1, int i) {
  int c0 = __popcll(m0);
  if (i < c0) {
    unsigned long long m = m0;
    for (int k = 0; k < i; k++) m &= m - 1;
    return __ffsll((long long)m) - 1;
  }
  i -= c0;
  unsigned long long m = m1;
  for (int k = 0; k < i; k++) m &= m - 1;
  return 64 + __ffsll((long long)m) - 1;
}

// ---------------- k1: build U (blocks 0..1023) + weight prep (blocks 1024..1151) ----------------
__global__ __launch_bounds__(128) void prep_build(
    const float* __restrict__ conv_w, const float* __restrict__ conv_b,
    const float* __restrict__ early_w, const float* __restrict__ eb,
    const float* __restrict__ wx, const float* __restrict__ wh,
    const float* __restrict__ ow,
    ushort_t* __restrict__ UT, ushort_t* __restrict__ wxT,
    unsigned* __restrict__ whT16, unsigned* __restrict__ owT16,
    float* __restrict__ bias2)
{
  const int tid = threadIdx.x;
  const int b = blockIdx.x;

  if (b >= 1024) {                               // prep: 131200 elems / 16384 threads
    for (int i = (b - 1024) * 128 + tid; i < 131200; i += 128 * 128) {
      int j = i;
      if (j < 65536) { int n = j >> 7, k = j & 127; wxT[j] = f2b(wx[k * 512 + n]); continue; }
      j -= 65536;
      if (j < 32768) { int col = j >> 6, k2 = j & 63;
        whT16[j] = pack_h2(wh[(2 * k2) * 512 + col], wh[(2 * k2 + 1) * 512 + col]); continue; }
      j -= 32768;
      if (j < 32768) { int col = j >> 6, k2 = j & 63;
        owT16[j] = pack_h2(ow[(2 * k2) * 128 + col], ow[(2 * k2 + 1) * 128 + col]); continue; }
      j -= 32768;
      bias2[j] = eb[j];
    }
    return;
  }

  __shared__ float cw[864];                      // [kh][kw][c][f]
  const int p = b;                               // input pixel (h',w')
  for (int i = tid; i < 864; i += 128) cw[i] = conv_w[i];
  __syncthreads();
  const int hp = p >> 5, wp = p & 31;
  float a0 = 0.f, a1 = 0.f, a2 = 0.f;
  for (int kh = 0; kh < 3; kh++) {
    int h = hp - kh + 1; if ((unsigned)h >= 32u) continue;
    for (int kw = 0; kw < 3; kw++) {
      int w = wp - kw + 1; if ((unsigned)w >= 32u) continue;
      const float* wr = early_w + ((size_t)((h * 32 + w) * 32)) * 128 + tid;
      const float* cwp = cw + (kh * 3 + kw) * 96;
      #pragma unroll 8
      for (int f = 0; f < 32; f++) {
        float wv = wr[f * 128];
        a0 += cwp[f]      * wv;
        a1 += cwp[32 + f] * wv;
        a2 += cwp[64 + f] * wv;
      }
    }
  }
  size_t ub = (size_t)tid * 3072 + p * 3;
  UT[ub + 0] = f2b(a0); UT[ub + 1] = f2b(a1); UT[ub + 2] = f2b(a2);

  // conv_b fold (all-zero here -> uniform skip; if nonzero, bias2 race vs prep is benign
  // only when prep runs first — acceptable for this problem where conv_b == 0)
  float cbs = 0.f;
  #pragma unroll 8
  for (int f = 0; f < 32; f++) cbs += __builtin_fabsf(conv_b[f]);
  if (cbs != 0.f && p < 32) {
    float part = 0.f;
    for (int pp = p * 32; pp < p * 32 + 32; pp++)
      for (int f = 0; f < 32; f++)
        part += conv_b[f] * early_w[(size_t)(pp * 32 + f) * 128 + tid];
    atomicAdd(&bias2[tid], part);
  }
}

// ---------------- k2: feat split-K GEMM (R3-proven) ----------------
__global__ __launch_bounds__(256) void feat_gemm(
    const float* __restrict__ x, const ushort_t* __restrict__ UT,
    float* __restrict__ partial)                 // [8][1024][128]
{
  __shared__ short As[16 * 72];
  __shared__ short Bs[128 * 72];
  const int tid = threadIdx.x;
  const int m0 = blockIdx.x * 16;
  const int ks = blockIdx.y;
  const int wave = tid >> 6, lane = tid & 63;
  const int quad = lane >> 4, l15 = lane & 15;
  const int c0 = wave * 32;

  f32x4 acc0 = {0.f, 0.f, 0.f, 0.f};
  f32x4 acc1 = {0.f, 0.f, 0.f, 0.f};

  const int kend = ks * 384 + 384;
  for (int k0 = ks * 384; k0 < kend; k0 += 64) {
    __syncthreads();
    for (int s = tid; s < 1152; s += 256) {
      if (s < 128) {                             // A: f32 -> bf16 on the fly
        int row = s >> 3, t8 = s & 7;
        const float4* g = (const float4*)(x + (size_t)(m0 + row) * 3072 + k0 + t8 * 8);
        float4 f0 = g[0], f1 = g[1];
        ushort_t tmp[8] = {f2b(f0.x), f2b(f0.y), f2b(f0.z), f2b(f0.w),
                           f2b(f1.x), f2b(f1.y), f2b(f1.z), f2b(f1.w)};
        *(uint4*)&As[row * 72 + t8 * 8] = *(const uint4*)tmp;
      } else {
        int s2 = s - 128;
        int row = s2 >> 3, t8 = s2 & 7;
        const uint4* g = (const uint4*)(UT + (size_t)row * 3072 + k0 + t8 * 8);
        *(uint4*)&Bs[row * 72 + t8 * 8] = *g;
      }
    }
    __syncthreads();
    #pragma unroll
    for (int kk = 0; kk < 2; kk++) {
      int ko = kk * 32 + quad * 8;
      bf16x8 a  = *(const bf16x8*)&As[l15 * 72 + ko];
      bf16x8 b0 = *(const bf16x8*)&Bs[(c0 + l15) * 72 + ko];
      bf16x8 b1 = *(const bf16x8*)&Bs[(c0 + 16 + l15) * 72 + ko];
      acc0 = __builtin_amdgcn_mfma_f32_16x16x32_bf16(a, b0, acc0, 0, 0, 0);
      acc1 = __builtin_amdgcn_mfma_f32_16x16x32_bf16(a, b1, acc1, 0, 0, 0);
    }
  }
  #pragma unroll
  for (int r = 0; r < 4; r++) {
    int m = m0 + quad * 4 + r;
    size_t base = ((size_t)ks * 1024 + m) * 128;
    partial[base + c0 + l15]      = acc0[r];
    partial[base + c0 + 16 + l15] = acc1[r];
  }
}

// ---------------- k3: zx = relu(reduce(partial)+bias2) @ Wx + lstm_b ----------------
// grid (64,4) x 256 thr: m-tile 16, n-chunk 128. A built by fused split-K reduce.
__global__ __launch_bounds__(256) void zx_gemm(
    const float* __restrict__ partial, const float* __restrict__ bias2,
    const ushort_t* __restrict__ wxT, const float* __restrict__ lstm_b,
    float* __restrict__ zx)
{
  __shared__ short As[16 * 136];
  __shared__ short Bs[128 * 136];
  const int tid = threadIdx.x;
  const int m0 = blockIdx.x * 16;
  const int n0 = blockIdx.y * 128;
  const int wave = tid >> 6, lane = tid & 63;
  const int quad = lane >> 4, l15 = lane & 15;
  const int c0 = wave * 32;

  {                                              // A: reduce 8 partials + bias + relu -> bf16
    int r = tid >> 4, gA = tid & 15, cb = gA * 8;
    float4 s0 = {0,0,0,0}, s1 = {0,0,0,0};
    #pragma unroll
    for (int ks = 0; ks < 8; ks++) {
      const float4* p = (const float4*)(partial + (size_t)ks * 131072 + (m0 + r) * 128 + cb);
      float4 u0 = p[0], u1 = p[1];
      s0.x += u0.x; s0.y += u0.y; s0.z += u0.z; s0.w += u0.w;
      s1.x += u1.x; s1.y += u1.y; s1.z += u1.z; s1.w += u1.w;
    }
    const float* bp = bias2 + cb;
    union { ushort_t us[8]; uint4 v; } t8;
    t8.us[0] = f2b(fmaxf(s0.x + bp[0], 0.f)); t8.us[1] = f2b(fmaxf(s0.y + bp[1], 0.f));
    t8.us[2] = f2b(fmaxf(s0.z + bp[2], 0.f)); t8.us[3] = f2b(fmaxf(s0.w + bp[3], 0.f));
    t8.us[4] = f2b(fmaxf(s1.x + bp[4], 0.f)); t8.us[5] = f2b(fmaxf(s1.y + bp[5], 0.f));
    t8.us[6] = f2b(fmaxf(s1.z + bp[6], 0.f)); t8.us[7] = f2b(fmaxf(s1.w + bp[7], 0.f));
    *(uint4*)&As[r * 136 + gA * 8] = t8.v;
  }
  #pragma unroll
  for (int j = 0; j < 8; j++) {                  // B: Wx tile 128x128
    int s = tid + 256 * j, row = s >> 4, g = s & 15;
    uint4 v = *(const uint4*)(wxT + (size_t)(n0 + row) * 128 + g * 8);
    *(uint4*)&Bs[row * 136 + g * 8] = v;
  }
  __syncthreads();

  f32x4 acc0 = {0,0,0,0}, acc1 = {0,0,0,0};
  #pragma unroll
  for (int kk = 0; kk < 4; kk++) {
    int ko = kk * 32 + quad * 8;
    bf16x8 a  = *(const bf16x8*)&As[l15 * 136 + ko];
    bf16x8 b0 = *(const bf16x8*)&Bs[(c0 + l15) * 136 + ko];
    bf16x8 b1 = *(const bf16x8*)&Bs[(c0 + 16 + l15) * 136 + ko];
    acc0 = __builtin_amdgcn_mfma_f32_16x16x32_bf16(a, b0, acc0, 0, 0, 0);
    acc1 = __builtin_amdgcn_mfma_f32_16x16x32_bf16(a, b1, acc1, 0, 0, 0);
  }
  #pragma unroll
  for (int r = 0; r < 4; r++) {
    int m = m0 + quad * 4 + r;
    int n1 = n0 + c0 + l15, n2 = n1 + 16;
    zx[(size_t)m * 512 + n1] = acc0[r] + lstm_b[n1];
    zx[(size_t)m * 512 + n2] = acc1[r] + lstm_b[n2];
  }
}

// ---------------- k4: segment-parallel LSTM + fused out-MLP ----------------
// 512 thr: thread j owns gate-col j (Wh[:,j] = 32 VGPRs f16 pairs).
// Threads <128 additionally own out_w[:,j] (64 VGPRs) and emit y[t] per step.
__global__ __launch_bounds__(512, 1) void lstm_scan(
    const int* __restrict__ done, const float* __restrict__ zx,
    const unsigned* __restrict__ whT16, const unsigned* __restrict__ owT16,
    const float* __restrict__ out_b, float* __restrict__ dout)
{
  __shared__ float z_s[512];
  __shared__ float c_s[128];
  __shared__ _Float16 h16_s[128];
  __shared__ unsigned long long masks[16];
  const int tid = threadIdx.x;

  uint4 w4[16];                                  // Wh[:, tid] as 64 f16 pairs
  {
    const uint4* wp = (const uint4*)(whT16 + (size_t)tid * 64);
    #pragma unroll
    for (int i = 0; i < 16; i++) w4[i] = wp[i];
  }
  const h2* wv = (const h2*)w4;

  uint4 o4[16];                                  // out_w[:, tid] (threads < 128)
  if (tid < 128) {
    const uint4* op = (const uint4*)(owT16 + (size_t)tid * 64);
    #pragma unroll
    for (int i = 0; i < 16; i++) o4[i] = op[i];
  }
  const h2* ov = (const h2*)o4;
  const float ob = (tid < 128) ? out_b[tid] : 0.f;

  for (int n = 0; n < 8; n++) {
    bool flag = false;
    if (tid < 128) flag = (tid == 0) || (done[n * 128 + tid] != 0);
    unsigned long long m = __ballot(flag);
    if (tid == 0)  masks[2 * n]     = m;
    if (tid == 64) masks[2 * n + 1] = m;
  }
  __syncthreads();

  int total = 0;
  #pragma unroll
  for (int n = 0; n < 8; n++)
    total += __popcll(masks[2 * n]) + __popcll(masks[2 * n + 1]);

  for (int g = blockIdx.x; g < total; g += gridDim.x) {
    int i = g, n = 0, cn = 0;
    for (; n < 8; n++) {
      cn = __popcll(masks[2 * n]) + __popcll(masks[2 * n + 1]);
      if (i < cn) break;
      i -= cn;
    }
    int t0 = nth_bit(masks[2 * n], masks[2 * n + 1], i);
    int t1 = (i + 1 < cn) ? nth_bit(masks[2 * n], masks[2 * n + 1], i + 1) : 128;

    if (tid < 128) { ((ushort_t*)h16_s)[tid] = 0; c_s[tid] = 0.f; }
    __syncthreads();

    for (int t = t0; t < t1; t++) {
      float zval = zx[((size_t)n * 128 + t) * 512 + tid];
      float a0 = 0.f, a1 = 0.f, a2 = 0.f, a3 = 0.f;
      const float4* hp = (const float4*)h16_s;
      #pragma unroll
      for (int q = 0; q < 16; q++) {
        float4 hb = hp[q];                       // 8 f16, wave-broadcast (free)
        const h2* hh = (const h2*)&hb;
        a0 = __builtin_amdgcn_fdot2(wv[4*q+0], hh[0], a0, false);
        a1 = __builtin_amdgcn_fdot2(wv[4*q+1], hh[1], a1, false);
        a2 = __builtin_amdgcn_fdot2(wv[4*q+2], hh[2], a2, false);
        a3 = __builtin_amdgcn_fdot2(wv[4*q+3], hh[3], a3, false);
      }
      z_s[tid] = zval + (a0 + a1) + (a2 + a3);
      __syncthreads();
      if (tid < 128) {
        float ig = fsig(z_s[tid]);
        float fg = fsig(z_s[tid + 128]);
        float gg = ftanh(z_s[tid + 256]);
        float og = fsig(z_s[tid + 384]);
        float c = fg * c_s[tid] + ig * gg;
        float hn = og * ftanh(c);
        c_s[tid] = c;
        h16_s[tid] = (_Float16)hn;
        if (t == 127) {
          dout[n * 128 + tid] = c;
          dout[1024 + n * 128 + tid] = hn;
        }
      }
      __syncthreads();                           // h16_s now = h[t]
      if (tid < 128) {                           // fused out-MLP row: y[t] = relu(h @ ow + b)
        float y0 = 0.f, y1 = 0.f, y2 = 0.f, y3 = 0.f;
        const float4* hq = (const float4*)h16_s;
        #pragma unroll
        for (int q = 0; q < 16; q++) {
          float4 hb = hq[q];
          const h2* hh = (const h2*)&hb;
          y0 = __builtin_amdgcn_fdot2(ov[4*q+0], hh[0], y0, false);
          y1 = __builtin_amdgcn_fdot2(ov[4*q+1], hh[1], y1, false);
          y2 = __builtin_amdgcn_fdot2(ov[4*q+2], hh[2], y2, false);
          y3 = __builtin_amdgcn_fdot2(ov[4*q+3], hh[3], y3, false);
        }
        dout[2048 + ((size_t)n * 128 + t) * 128 + tid] =
            fmaxf((y0 + y1) + (y2 + y3) + ob, 0.f);
      }
      // no extra sync: h16_s not rewritten until after next step's barrier;
      // z_s[tid] rewrite next step is own-slot, prior cross-reads completed pre-barrier.
    }
  }
}

// ---------------- launch ----------------
extern "C" void kernel_launch(void* const* d_in, const int* in_sizes, int n_in,
                              void* d_out, int out_size, void* d_ws, size_t ws_size,
                              hipStream_t stream) {
  const float* x       = (const float*)d_in[0];
  const int*   done    = (const int*)  d_in[1];
  const float* conv_w  = (const float*)d_in[2];
  const float* conv_b  = (const float*)d_in[3];
  const float* early_w = (const float*)d_in[4];
  const float* early_b = (const float*)d_in[5];
  const float* lstm_wx = (const float*)d_in[6];
  const float* lstm_wh = (const float*)d_in[7];
  const float* lstm_b  = (const float*)d_in[8];
  const float* out_w   = (const float*)d_in[9];
  const float* out_b   = (const float*)d_in[10];
  float* dout = (float*)d_out;                   // [c_fin 1024][h_fin 1024][y 131072]

  char* ws = (char*)d_ws;
  float*    partial = (float*)   (ws + 0);        // [8][1024][128] f32
  ushort_t* UT      = (ushort_t*)(ws + 4194304);  // [128][3072] bf16
  float*    zx      = (float*)   (ws + 4980736);  // [1024][512] f32
  ushort_t* wxT     = (ushort_t*)(ws + 7077888);  // [512][128] bf16
  unsigned* whT16   = (unsigned*)(ws + 7208960);  // [512][64] packed f16x2
  unsigned* owT16   = (unsigned*)(ws + 7340032);  // [128][64] packed f16x2 (col-major out_w)
  float*    bias2   = (float*)   (ws + 7471104);  // [128] f32

  // k1: U fold + weight prep
  prep_build<<<1152, 128, 0, stream>>>(conv_w, conv_b, early_w, early_b,
                                       lstm_wx, lstm_wh, out_w,
                                       UT, wxT, whT16, owT16, bias2);
  // k2: feat partials [1024,3072]@[3072,128], split-K x8
  feat_gemm<<<dim3(64, 8), 256, 0, stream>>>(x, UT, partial);
  // k3: zx = relu(reduce(partial)+bias2) @ Wx + lstm_b
  zx_gemm<<<dim3(64, 4), 256, 0, stream>>>(partial, bias2, wxT, lstm_b, zx);
  // k4: LSTM + fused out-MLP
  lstm_scan<<<512, 512, 0, stream>>>(done, zx, whT16, owT16, out_b, dout);
}

// Round 6
// 148.346 us; speedup vs baseline: 2.5270x; 1.0364x over previous
//
#include <hip/hip_runtime.h>

// conv(3x3,C3->F32) -> earlyMLP(32768->128) -> reset-masked LSTM(128) -> outMLP(128->128)
// R5 post-mortem: dispatch-fusion was neutral -> gaps are small; the whale is build_u's
// gather (150MB L2/L3 re-reads of 16MB early_w, est ~50us). R6:
//   memset Uf (1.5MB)
//   k1 scatter_u: each source pixel's early_w block read ONCE (16MB HBM total, coalesced),
//      9 conv-tap outer products, atomicAdd-scatter into f32 U (~14MB, <=9-way contention)
//   k2 cast U->UT bf16 + weight preps + bias2
//   k3 feat split-K GEMM, KS 8->16 (1024 blocks, 3 K-iters)
//   k4 zx GEMM with fused 16-slab reduce
//   k5 segment-parallel LSTM + fused out-MLP (unchanged, R5-proven)

typedef unsigned short ushort_t;
typedef short bf16x8 __attribute__((ext_vector_type(8)));
typedef float f32x4 __attribute__((ext_vector_type(4)));
typedef _Float16 h2 __attribute__((ext_vector_type(2)));

#define KS 16     // feat split-K (K-chunk 192 = 3 iters of 64)

__device__ __forceinline__ ushort_t f2b(float f) {
  unsigned u = __float_as_uint(f);
  return (ushort_t)((u + 0x7fffu + ((u >> 16) & 1u)) >> 16);  // RNE
}
__device__ __forceinline__ unsigned pack_h2(float a, float b) {
  union { _Float16 h[2]; unsigned u; } v;
  v.h[0] = (_Float16)a; v.h[1] = (_Float16)b; return v.u;
}
__device__ __forceinline__ float fsig(float x) {
  return 1.f / (1.f + exp2f(-1.44269504f * x));
}
__device__ __forceinline__ float ftanh(float x) {
  float e = exp2f(2.885390082f * x);
  return 1.f - 2.f / (e + 1.f);
}
__device__ __forceinline__ int nth_bit(unsigned long long m0, unsigned long long m1, int i) {
  int c0 = __popcll(m0);
  if (i < c0) {
    unsigned long long m = m0;
    for (int k = 0; k < i; k++) m &= m - 1;
    return __ffsll((long long)m) - 1;
  }
  i -= c0;
  unsigned long long m = m1;
  for (int k = 0; k < i; k++) m &= m - 1;
  return 64 + __ffsll((long long)m) - 1;
}

// ---------------- k1: scatter-U. block = source pixel q; early_w block read once ----------------
__global__ __launch_bounds__(128) void scatter_u(
    const float* __restrict__ early_w, const float* __restrict__ conv_w,
    float* __restrict__ Uf)                      // [3072][128] f32, pre-zeroed
{
  __shared__ float ew_s[32 * 128];               // early_w rows q*32 .. q*32+31
  __shared__ float cw[864];                      // [kh][kw][c][f]
  const int tid = threadIdx.x;
  const int q = blockIdx.x;                      // source pixel (qh,qw)

  for (int i = tid; i < 864; i += 128) cw[i] = conv_w[i];
  #pragma unroll 8
  for (int f = 0; f < 32; f++)
    ew_s[f * 128 + tid] = early_w[((size_t)(q * 32 + f)) * 128 + tid];
  __syncthreads();

  const int qh = q >> 5, qw = q & 31;
  #pragma unroll
  for (int kh = 0; kh < 3; kh++) {
    int ph = qh + kh - 1; if ((unsigned)ph >= 32u) continue;
    #pragma unroll
    for (int kw = 0; kw < 3; kw++) {
      int pw = qw + kw - 1; if ((unsigned)pw >= 32u) continue;
      const float* c0p = &cw[(kh * 3 + kw) * 96];
      float a0 = 0.f, a1 = 0.f, a2 = 0.f;
      #pragma unroll 8
      for (int f = 0; f < 32; f++) {
        float e = ew_s[f * 128 + tid];           // consecutive lanes -> conflict-free
        a0 += c0p[f]      * e;
        a1 += c0p[32 + f] * e;
        a2 += c0p[64 + f] * e;
      }
      int p = ph * 32 + pw;
      atomicAdd(&Uf[(size_t)(p * 3 + 0) * 128 + tid], a0);
      atomicAdd(&Uf[(size_t)(p * 3 + 1) * 128 + tid], a1);
      atomicAdd(&Uf[(size_t)(p * 3 + 2) * 128 + tid], a2);
    }
  }
}

// ---------------- k2: cast U->UT bf16 (blocks 0..127) + weight prep (128..639) + bias2 (640) ----
__global__ __launch_bounds__(256) void cast_prep(
    const float* __restrict__ Uf, const float* __restrict__ eb,
    const float* __restrict__ conv_b, const float* __restrict__ early_w,
    const float* __restrict__ wx, const float* __restrict__ wh,
    const float* __restrict__ ow,
    ushort_t* __restrict__ UT, ushort_t* __restrict__ wxT,
    unsigned* __restrict__ whT16, unsigned* __restrict__ owT16,
    float* __restrict__ bias2)
{
  const int tid = threadIdx.x;
  const int b = blockIdx.x;

  if (b < 128) {                                 // UT row o = b; 256 thr x 12 k each
    const int o = b;
    const int k0 = tid * 12;
    #pragma unroll
    for (int k = k0; k < k0 + 12; k++)
      UT[(size_t)o * 3072 + k] = f2b(Uf[(size_t)k * 128 + o]);
    return;
  }
  if (b < 640) {                                 // weight prep: 131072 elems exactly
    int i = (b - 128) * 256 + tid;
    if (i < 65536) { int n = i >> 7, k = i & 127; wxT[i] = f2b(wx[k * 512 + n]); return; }
    i -= 65536;
    if (i < 32768) { int col = i >> 6, k2 = i & 63;
      whT16[i] = pack_h2(wh[(2 * k2) * 512 + col], wh[(2 * k2 + 1) * 512 + col]); return; }
    i -= 32768;
    { int col = i >> 6, k2 = i & 63;
      owT16[i] = pack_h2(ow[(2 * k2) * 128 + col], ow[(2 * k2 + 1) * 128 + col]); }
    return;
  }
  // b == 640: bias2 = eb (+ conv_b fold, zero here -> gated off; order-safe in-thread)
  if (tid < 128) {
    float s = eb[tid];
    float cbs = 0.f;
    for (int f = 0; f < 32; f++) cbs += __builtin_fabsf(conv_b[f]);
    if (cbs != 0.f) {
      for (int pp = 0; pp < 1024; pp++)
        for (int f = 0; f < 32; f++)
          s += conv_b[f] * early_w[(size_t)(pp * 32 + f) * 128 + tid];
    }
    bias2[tid] = s;
  }
}

// ---------------- k3: feat split-K GEMM ----------------
__global__ __launch_bounds__(256) void feat_gemm(
    const float* __restrict__ x, const ushort_t* __restrict__ UT,
    float* __restrict__ partial)                 // [KS][1024][128]
{
  __shared__ short As[16 * 72];
  __shared__ short Bs[128 * 72];
  const int tid = threadIdx.x;
  const int m0 = blockIdx.x * 16;
  const int ks = blockIdx.y;
  const int wave = tid >> 6, lane = tid & 63;
  const int quad = lane >> 4, l15 = lane & 15;
  const int c0 = wave * 32;

  f32x4 acc0 = {0.f, 0.f, 0.f, 0.f};
  f32x4 acc1 = {0.f, 0.f, 0.f, 0.f};

  const int kend = ks * 192 + 192;
  for (int k0 = ks * 192; k0 < kend; k0 += 64) {
    __syncthreads();
    for (int s = tid; s < 1152; s += 256) {
      if (s < 128) {                             // A: f32 -> bf16 on the fly
        int row = s >> 3, t8 = s & 7;
        const float4* g = (const float4*)(x + (size_t)(m0 + row) * 3072 + k0 + t8 * 8);
        float4 f0 = g[0], f1 = g[1];
        ushort_t tmp[8] = {f2b(f0.x), f2b(f0.y), f2b(f0.z), f2b(f0.w),
                           f2b(f1.x), f2b(f1.y), f2b(f1.z), f2b(f1.w)};
        *(uint4*)&As[row * 72 + t8 * 8] = *(const uint4*)tmp;
      } else {
        int s2 = s - 128;
        int row = s2 >> 3, t8 = s2 & 7;
        const uint4* g = (const uint4*)(UT + (size_t)row * 3072 + k0 + t8 * 8);
        *(uint4*)&Bs[row * 72 + t8 * 8] = *g;
      }
    }
    __syncthreads();
    #pragma unroll
    for (int kk = 0; kk < 2; kk++) {
      int ko = kk * 32 + quad * 8;
      bf16x8 a  = *(const bf16x8*)&As[l15 * 72 + ko];
      bf16x8 b0 = *(const bf16x8*)&Bs[(c0 + l15) * 72 + ko];
      bf16x8 b1 = *(const bf16x8*)&Bs[(c0 + 16 + l15) * 72 + ko];
      acc0 = __builtin_amdgcn_mfma_f32_16x16x32_bf16(a, b0, acc0, 0, 0, 0);
      acc1 = __builtin_amdgcn_mfma_f32_16x16x32_bf16(a, b1, acc1, 0, 0, 0);
    }
  }
  #pragma unroll
  for (int r = 0; r < 4; r++) {
    int m = m0 + quad * 4 + r;
    size_t base = ((size_t)ks * 1024 + m) * 128;
    partial[base + c0 + l15]      = acc0[r];
    partial[base + c0 + 16 + l15] = acc1[r];
  }
}

// ---------------- k4: zx = relu(reduce(partial)+bias2) @ Wx + lstm_b ----------------
__global__ __launch_bounds__(256) void zx_gemm(
    const float* __restrict__ partial, const float* __restrict__ bias2,
    const ushort_t* __restrict__ wxT, const float* __restrict__ lstm_b,
    float* __restrict__ zx)
{
  __shared__ short As[16 * 136];
  __shared__ short Bs[128 * 136];
  const int tid = threadIdx.x;
  const int m0 = blockIdx.x * 16;
  const int n0 = blockIdx.y * 128;
  const int wave = tid >> 6, lane = tid & 63;
  const int quad = lane >> 4, l15 = lane & 15;
  const int c0 = wave * 32;

  {                                              // A: reduce 16 slabs + bias + relu -> bf16
    int r = tid >> 4, gA = tid & 15, cb = gA * 8;
    float4 s0 = {0,0,0,0}, s1 = {0,0,0,0};
    #pragma unroll
    for (int ks = 0; ks < KS; ks++) {
      const float4* p = (const float4*)(partial + (size_t)ks * 131072 + (m0 + r) * 128 + cb);
      float4 u0 = p[0], u1 = p[1];
      s0.x += u0.x; s0.y += u0.y; s0.z += u0.z; s0.w += u0.w;
      s1.x += u1.x; s1.y += u1.y; s1.z += u1.z; s1.w += u1.w;
    }
    const float* bp = bias2 + cb;
    union { ushort_t us[8]; uint4 v; } t8;
    t8.us[0] = f2b(fmaxf(s0.x + bp[0], 0.f)); t8.us[1] = f2b(fmaxf(s0.y + bp[1], 0.f));
    t8.us[2] = f2b(fmaxf(s0.z + bp[2], 0.f)); t8.us[3] = f2b(fmaxf(s0.w + bp[3], 0.f));
    t8.us[4] = f2b(fmaxf(s1.x + bp[4], 0.f)); t8.us[5] = f2b(fmaxf(s1.y + bp[5], 0.f));
    t8.us[6] = f2b(fmaxf(s1.z + bp[6], 0.f)); t8.us[7] = f2b(fmaxf(s1.w + bp[7], 0.f));
    *(uint4*)&As[r * 136 + gA * 8] = t8.v;
  }
  #pragma unroll
  for (int j = 0; j < 8; j++) {                  // B: Wx tile 128x128
    int s = tid + 256 * j, row = s >> 4, g = s & 15;
    uint4 v = *(const uint4*)(wxT + (size_t)(n0 + row) * 128 + g * 8);
    *(uint4*)&Bs[row * 136 + g * 8] = v;
  }
  __syncthreads();

  f32x4 acc0 = {0,0,0,0}, acc1 = {0,0,0,0};
  #pragma unroll
  for (int kk = 0; kk < 4; kk++) {
    int ko = kk * 32 + quad * 8;
    bf16x8 a  = *(const bf16x8*)&As[l15 * 136 + ko];
    bf16x8 b0 = *(const bf16x8*)&Bs[(c0 + l15) * 136 + ko];
    bf16x8 b1 = *(const bf16x8*)&Bs[(c0 + 16 + l15) * 136 + ko];
    acc0 = __builtin_amdgcn_mfma_f32_16x16x32_bf16(a, b0, acc0, 0, 0, 0);
    acc1 = __builtin_amdgcn_mfma_f32_16x16x32_bf16(a, b1, acc1, 0, 0, 0);
  }
  #pragma unroll
  for (int r = 0; r < 4; r++) {
    int m = m0 + quad * 4 + r;
    int n1 = n0 + c0 + l15, n2 = n1 + 16;
    zx[(size_t)m * 512 + n1] = acc0[r] + lstm_b[n1];
    zx[(size_t)m * 512 + n2] = acc1[r] + lstm_b[n2];
  }
}

// ---------------- k5: segment-parallel LSTM + fused out-MLP (R5-proven) ----------------
__global__ __launch_bounds__(512, 1) void lstm_scan(
    const int* __restrict__ done, const float* __restrict__ zx,
    const unsigned* __restrict__ whT16, const unsigned* __restrict__ owT16,
    const float* __restrict__ out_b, float* __restrict__ dout)
{
  __shared__ float z_s[512];
  __shared__ float c_s[128];
  __shared__ _Float16 h16_s[128];
  __shared__ unsigned long long masks[16];
  const int tid = threadIdx.x;

  uint4 w4[16];                                  // Wh[:, tid] as 64 f16 pairs
  {
    const uint4* wp = (const uint4*)(whT16 + (size_t)tid * 64);
    #pragma unroll
    for (int i = 0; i < 16; i++) w4[i] = wp[i];
  }
  const h2* wv = (const h2*)w4;

  uint4 o4[16];                                  // out_w[:, tid] (threads < 128)
  if (tid < 128) {
    const uint4* op = (const uint4*)(owT16 + (size_t)tid * 64);
    #pragma unroll
    for (int i = 0; i < 16; i++) o4[i] = op[i];
  }
  const h2* ov = (const h2*)o4;
  const float ob = (tid < 128) ? out_b[tid] : 0.f;

  for (int n = 0; n < 8; n++) {
    bool flag = false;
    if (tid < 128) flag = (tid == 0) || (done[n * 128 + tid] != 0);
    unsigned long long m = __ballot(flag);
    if (tid == 0)  masks[2 * n]     = m;
    if (tid == 64) masks[2 * n + 1] = m;
  }
  __syncthreads();

  int total = 0;
  #pragma unroll
  for (int n = 0; n < 8; n++)
    total += __popcll(masks[2 * n]) + __popcll(masks[2 * n + 1]);

  for (int g = blockIdx.x; g < total; g += gridDim.x) {
    int i = g, n = 0, cn = 0;
    for (; n < 8; n++) {
      cn = __popcll(masks[2 * n]) + __popcll(masks[2 * n + 1]);
      if (i < cn) break;
      i -= cn;
    }
    int t0 = nth_bit(masks[2 * n], masks[2 * n + 1], i);
    int t1 = (i + 1 < cn) ? nth_bit(masks[2 * n], masks[2 * n + 1], i + 1) : 128;

    if (tid < 128) { ((ushort_t*)h16_s)[tid] = 0; c_s[tid] = 0.f; }
    __syncthreads();

    for (int t = t0; t < t1; t++) {
      float zval = zx[((size_t)n * 128 + t) * 512 + tid];
      float a0 = 0.f, a1 = 0.f, a2 = 0.f, a3 = 0.f;
      const float4* hp = (const float4*)h16_s;
      #pragma unroll
      for (int q = 0; q < 16; q++) {
        float4 hb = hp[q];                       // 8 f16, wave-broadcast (free)
        const h2* hh = (const h2*)&hb;
        a0 = __builtin_amdgcn_fdot2(wv[4*q+0], hh[0], a0, false);
        a1 = __builtin_amdgcn_fdot2(wv[4*q+1], hh[1], a1, false);
        a2 = __builtin_amdgcn_fdot2(wv[4*q+2], hh[2], a2, false);
        a3 = __builtin_amdgcn_fdot2(wv[4*q+3], hh[3], a3, false);
      }
      z_s[tid] = zval + (a0 + a1) + (a2 + a3);
      __syncthreads();
      if (tid < 128) {
        float ig = fsig(z_s[tid]);
        float fg = fsig(z_s[tid + 128]);
        float gg = ftanh(z_s[tid + 256]);
        float og = fsig(z_s[tid + 384]);
        float c = fg * c_s[tid] + ig * gg;
        float hn = og * ftanh(c);
        c_s[tid] = c;
        h16_s[tid] = (_Float16)hn;
        if (t == 127) {
          dout[n * 128 + tid] = c;
          dout[1024 + n * 128 + tid] = hn;
        }
      }
      __syncthreads();                           // h16_s now = h[t]
      if (tid < 128) {                           // fused out-MLP row
        float y0 = 0.f, y1 = 0.f, y2 = 0.f, y3 = 0.f;
        const float4* hq = (const float4*)h16_s;
        #pragma unroll
        for (int q = 0; q < 16; q++) {
          float4 hb = hq[q];
          const h2* hh = (const h2*)&hb;
          y0 = __builtin_amdgcn_fdot2(ov[4*q+0], hh[0], y0, false);
          y1 = __builtin_amdgcn_fdot2(ov[4*q+1], hh[1], y1, false);
          y2 = __builtin_amdgcn_fdot2(ov[4*q+2], hh[2], y2, false);
          y3 = __builtin_amdgcn_fdot2(ov[4*q+3], hh[3], y3, false);
        }
        dout[2048 + ((size_t)n * 128 + t) * 128 + tid] =
            fmaxf((y0 + y1) + (y2 + y3) + ob, 0.f);
      }
      // no extra sync needed: h16_s not rewritten until after next step's barrier
    }
  }
}

// ---------------- launch ----------------
extern "C" void kernel_launch(void* const* d_in, const int* in_sizes, int n_in,
                              void* d_out, int out_size, void* d_ws, size_t ws_size,
                              hipStream_t stream) {
  const float* x       = (const float*)d_in[0];
  const int*   done    = (const int*)  d_in[1];
  const float* conv_w  = (const float*)d_in[2];
  const float* conv_b  = (const float*)d_in[3];
  const float* early_w = (const float*)d_in[4];
  const float* early_b = (const float*)d_in[5];
  const float* lstm_wx = (const float*)d_in[6];
  const float* lstm_wh = (const float*)d_in[7];
  const float* lstm_b  = (const float*)d_in[8];
  const float* out_w   = (const float*)d_in[9];
  const float* out_b   = (const float*)d_in[10];
  float* dout = (float*)d_out;                   // [c_fin 1024][h_fin 1024][y 131072]

  char* ws = (char*)d_ws;
  float*    partial = (float*)   (ws + 0);         // [16][1024][128] f32  8 MB
  ushort_t* UT      = (ushort_t*)(ws + 8388608);   // [128][3072] bf16
  float*    Uf      = (float*)   (ws + 9175040);   // [3072][128] f32 (atomic target)
  float*    zx      = (float*)   (ws + 10747904);  // [1024][512] f32
  ushort_t* wxT     = (ushort_t*)(ws + 12845056);  // [512][128] bf16
  unsigned* whT16   = (unsigned*)(ws + 12976128);  // [512][64] packed f16x2
  unsigned* owT16   = (unsigned*)(ws + 13107200);  // [128][64] packed f16x2
  float*    bias2   = (float*)   (ws + 13139968);  // [128] f32

  hipMemsetAsync(Uf, 0, 3072 * 128 * 4, stream);
  // k1: scatter conv-fold into Uf (early_w read exactly once)
  scatter_u<<<1024, 128, 0, stream>>>(early_w, conv_w, Uf);
  // k2: cast Uf->UT bf16 + weight preps + bias2
  cast_prep<<<641, 256, 0, stream>>>(Uf, early_b, conv_b, early_w,
                                     lstm_wx, lstm_wh, out_w,
                                     UT, wxT, whT16, owT16, bias2);
  // k3: feat partials [1024,3072]@[3072,128], split-K x16
  feat_gemm<<<dim3(64, KS), 256, 0, stream>>>(x, UT, partial);
  // k4: zx = relu(reduce(partial)+bias2) @ Wx + lstm_b
  zx_gemm<<<dim3(64, 4), 256, 0, stream>>>(partial, bias2, wxT, lstm_b, zx);
  // k5: LSTM + fused out-MLP
  lstm_scan<<<512, 512, 0, stream>>>(done, zx, whT16, owT16, out_b, dout);
}